// Round 10
// baseline (112.214 us; speedup 1.0000x reference)
//
#include <hip/hip_runtime.h>

// YOLOv1 loss on MI355X — direct float4 loads + spread-atomic accumulation
// + fused last-block finalize (2 dispatches: memset, main).
//
// Session findings:
//  * Same-line atomic drain (~17 ns/atomic, serialized) dominated R1-R5;
//    spreading partials across 64 distinct 64-B lines fixed it (127->46 us).
//  * Block-lockstep access is cache-friendly; wave-private free-running
//    staging regressed (R7, FETCH +56%). LDS staging == direct strided loads
//    (46.0 vs 45.6 us) -> keep simple direct loads.
//  * R8/R9: three structures converge at ~46 us; counters clean
//    (FETCH=input-exact 111MB, WRITE~0, VALUBusy 13%). Residual = 3-dispatch
//    serial chain. This round fuses finalize into main via last-block ticket.
//
// Inputs (setup_inputs order):
//   d_in[0] bounding_boxes: (16384,12,12,12) f32
//   d_in[1] ground_truth:   (16384,12,12,1,12) f32
//   d_in[2] grid_size: int scalar (8)
//   d_in[3] img_size:  int scalar (96)
// Output: 6 f32: loss, l_coord, loss_confidence, l_cls, iou_sum, object_num

#define S_DIM 12
#define CELLS_PER_IMG (S_DIM * S_DIM)      // 144
#define NCELLS (16384 * CELLS_PER_IMG)     // 2,359,296 = 2304 * 256 * 4
#define GRID_BLKS 2304
#define ITERS 4
#define CELL_STRIDE (GRID_BLKS * 256)
#define NROWS 64                            // spread-atomic rows (64 B apart)
#define ROWF 16                             // floats per row (64 B)
#define WS_FLOATS (NROWS * ROWF)            // 1024 floats; counter lives after
#define L_COORD_C 5.0f
#define L_NOOBJ_C 0.5f

__device__ __forceinline__ float sq_sqrt(float t) {
    return sqrtf(fmaxf(t, 0.0f) + 1e-08f);
}

__global__ __launch_bounds__(256) void yolo_loss_main(
    const float4* __restrict__ bb4,
    const float4* __restrict__ gt4,
    const int* __restrict__ gs_p,
    const int* __restrict__ im_p,
    float* __restrict__ ws,
    float* __restrict__ out)
{
    const float gs = (float)(*gs_p);
    const float im = (float)(*im_p);
    const float im1 = im - 1.0f;

    float s_conf = 0.0f, s_coord = 0.0f, s_cls = 0.0f, s_iou = 0.0f, s_obj = 0.0f;

    const int base = blockIdx.x * 256 + threadIdx.x;

    #pragma unroll
    for (int it = 0; it < ITERS; ++it) {
        const int n = base + it * CELL_STRIDE;   // lane-adjacent cells
        const float4* pb = bb4 + (size_t)n * 3;
        const float4* pg = gt4 + (size_t)n * 3;

        const float4 b0 = pb[0];   // x1,y1,w1,h1
        const float4 b1 = pb[1];   // c1,x2,y2,w2
        const float4 b2 = pb[2];   // h2,c2,cls0,cls1
        const float4 g0 = pg[0];   // x,y,w,h
        const float4 g1 = pg[1];   // conf,l,u,r
        const float4 g2 = pg[2];   // d,obj,cls0,cls1

        const float c1 = b1.x;
        const float c2 = b2.y;
        const bool sel2 = c1 < c2;

        const float p0 = sel2 ? b1.y : b0.x;
        const float p1 = sel2 ? b1.z : b0.y;
        const float p2 = sel2 ? b1.w : b0.z;
        const float p3 = sel2 ? b2.x : b0.w;
        const float p4 = sel2 ? c2   : c1;    // sel_conf
        const float other = sel2 ? c1 : c2;   // other_conf

        const bool obj = (g2.y != 0.0f);
        const float objf = obj ? 1.0f : 0.0f;

        // confidence losses
        float conf_c = L_NOOBJ_C * other * other;
        const float dconf = g1.x - p4;
        conf_c += obj ? (dconf * dconf) : (L_NOOBJ_C * p4 * p4);
        s_conf += conf_c;

        // coord loss
        const float dx = g0.x - p0;
        const float dy = g0.y - p1;
        const float dw = sq_sqrt(g0.z) - sq_sqrt(p2);
        const float dh = sq_sqrt(g0.w) - sq_sqrt(p3);
        s_coord += objf * (L_COORD_C * (dx*dx + dy*dy + dw*dw + dh*dh));

        // class loss
        const float dc0 = g2.z - b2.z;
        const float dc1 = g2.w - b2.w;
        s_cls += objf * (dc0*dc0 + dc1*dc1);

        // IoU
        const int rem = n % CELLS_PER_IMG;
        const int gi = rem / S_DIM;
        const int gj = rem % S_DIM;
        const float px = truncf((float)gj * gs + p0 * gs);
        const float py = truncf((float)gi * gs + p1 * gs);
        const float pw = truncf(p2 * im);
        const float ph = truncf(p3 * im);
        const float pl = fmaxf(0.0f, px - pw * 0.5f);
        const float pu = fmaxf(0.0f, py - ph * 0.5f);
        const float pr = fminf(im1, px + pw * 0.5f);
        const float pd = fminf(im1, py + ph * 0.5f);
        const float pA = (pr - pl) * (pd - pu);
        const float gl = g1.y, gu = g1.z, gr = g1.w, gd = g2.x;
        const float gA = (gr - gl) * (gd - gu);
        const float lx = fmaxf(pl, gl);
        const float rx = fminf(pr, gr);
        const float uy = fmaxf(pu, gu);
        const float dy2 = fminf(pd, gd);
        const float inter = (rx - lx) * (dy2 - uy);
        const float iou = ((rx < lx) || (dy2 < uy)) ? 0.0f : inter / (pA + gA - inter);
        s_iou += objf * iou;

        s_obj += objf;
    }

    // wave reduction
    #pragma unroll
    for (int off = 32; off > 0; off >>= 1) {
        s_conf  += __shfl_down(s_conf,  off);
        s_coord += __shfl_down(s_coord, off);
        s_cls   += __shfl_down(s_cls,   off);
        s_iou   += __shfl_down(s_iou,   off);
        s_obj   += __shfl_down(s_obj,   off);
    }

    __shared__ float red[4][5];
    __shared__ int islast;
    const int w = threadIdx.x >> 6;
    const int l = threadIdx.x & 63;
    if (l == 0) {
        red[w][0] = s_conf;
        red[w][1] = s_coord;
        red[w][2] = s_cls;
        red[w][3] = s_iou;
        red[w][4] = s_obj;
    }
    __syncthreads();
    if (threadIdx.x == 0) {
        float t0 = 0, t1 = 0, t2 = 0, t3 = 0, t4 = 0;
        #pragma unroll
        for (int v = 0; v < 4; ++v) {
            t0 += red[v][0]; t1 += red[v][1]; t2 += red[v][2];
            t3 += red[v][3]; t4 += red[v][4];
        }
        // spread accumulation: row (blockIdx & 63), each its own 64-B line
        float* row = ws + (size_t)(blockIdx.x & (NROWS - 1)) * ROWF;
        atomicAdd(&row[0], t0);  // conf
        atomicAdd(&row[1], t1);  // coord
        atomicAdd(&row[2], t2);  // cls
        atomicAdd(&row[3], t3);  // iou
        atomicAdd(&row[4], t4);  // obj count
        __threadfence();         // row-adds visible before ticket
        unsigned* cnt = (unsigned*)(ws + WS_FLOATS);
        const unsigned ticket = atomicAdd(cnt, 1u);
        islast = (ticket == GRID_BLKS - 1) ? 1 : 0;
    }
    __syncthreads();

    // last block: wave 0 reduces the 64 rows and writes the outputs.
    // Reads go through the atomic path (same coherence point as the adds)
    // to avoid any per-XCD L2 staleness.
    if (islast && threadIdx.x < 64) {
        float* row = ws + (size_t)threadIdx.x * ROWF;
        float a0 = atomicAdd(&row[0], 0.0f);
        float a1 = atomicAdd(&row[1], 0.0f);
        float a2 = atomicAdd(&row[2], 0.0f);
        float a3 = atomicAdd(&row[3], 0.0f);
        float a4 = atomicAdd(&row[4], 0.0f);
        #pragma unroll
        for (int off = 32; off > 0; off >>= 1) {
            a0 += __shfl_down(a0, off);
            a1 += __shfl_down(a1, off);
            a2 += __shfl_down(a2, off);
            a3 += __shfl_down(a3, off);
            a4 += __shfl_down(a4, off);
        }
        if (threadIdx.x == 0) {
            out[0] = a0 + a1 + a2;  // loss = conf + coord + cls
            out[1] = a1;            // l_coord
            out[2] = a0;            // loss_confidence
            out[3] = a2;            // l_cls
            out[4] = a3;            // iou_sum
            out[5] = a4;            // object_num
        }
    }
}

extern "C" void kernel_launch(void* const* d_in, const int* in_sizes, int n_in,
                              void* d_out, int out_size, void* d_ws, size_t ws_size,
                              hipStream_t stream) {
    const float4* bb4 = (const float4*)d_in[0];
    const float4* gt4 = (const float4*)d_in[1];
    const int* gs_p = (const int*)d_in[2];
    const int* im_p = (const int*)d_in[3];
    float* ws = (float*)d_ws;
    float* out = (float*)d_out;

    // zero 64 accumulator rows + ticket counter (deterministic each launch)
    hipMemsetAsync(d_ws, 0, WS_FLOATS * sizeof(float) + 64, stream);

    yolo_loss_main<<<GRID_BLKS, 256, 0, stream>>>(bb4, gt4, gs_p, im_p, ws, out);
}

// Round 12
// 103.812 us; speedup vs baseline: 1.0809x; 1.0809x over previous
//
#include <hip/hip_runtime.h>

// YOLOv1 loss on MI355X — direct float4 loads + spread-atomic accumulation
// + fused finalize via TWO-LEVEL ticket (2 graph nodes: memset, main).
//
// R11 post-mortem: fusion failed from a units bug — DONE offset computed in
// float-elements but applied in bytes, aliasing the done counter onto row
// 32's accumulator line; islast never fired and out stayed zero. All ws
// regions are now defined in BYTES and disjoint:
//   [0,    4096)  64 accumulator rows, one 64-B line each
//   [4096, 8192)  64 ticket lines, one 64-B line each
//   [8192, 8256)  done counter
//
// Session findings:
//  * Same-line atomic serialization ~17 ns each dominated R1-R5 (and R10's
//    single ticket: 2304 same-line adds ≈ +39 us; its per-block
//    __threadfence() also expensive). Spread across 64-B lines it's free.
//  * Release/acq_rel __hip_atomic ops = cheap ordering (vmcnt wait only).
//  * Block-lockstep streaming is cache-friendly; LDS staging == direct
//    strided float4 loads -> keep direct loads (R8 baseline, 45.5 us).
//
// Inputs: d_in[0] bb (16384,12,12,12) f32; d_in[1] gt (16384,12,12,1,12) f32;
//         d_in[2] grid_size int; d_in[3] img_size int.
// Output: 6 f32: loss, l_coord, loss_confidence, l_cls, iou_sum, object_num

#define S_DIM 12
#define CELLS_PER_IMG (S_DIM * S_DIM)      // 144
#define NCELLS (16384 * CELLS_PER_IMG)     // 2,359,296 = 2304 * 256 * 4
#define GRID_BLKS 2304
#define ITERS 4
#define CELL_STRIDE (GRID_BLKS * 256)
#define NROWS 64
#define ROWF 16                             // floats per row line (64 B)
#define BLOCKS_PER_ROW (GRID_BLKS / NROWS)  // 36
#define TICKET_BYTE 4096                    // after 64*64B rows
#define DONE_BYTE 8192                      // after 64*64B tickets
#define WS_BYTES (DONE_BYTE + 64)
#define L_COORD_C 5.0f
#define L_NOOBJ_C 0.5f

__device__ __forceinline__ float sq_sqrt(float t) {
    return sqrtf(fmaxf(t, 0.0f) + 1e-08f);
}

__global__ __launch_bounds__(256) void yolo_loss_main(
    const float4* __restrict__ bb4,
    const float4* __restrict__ gt4,
    const int* __restrict__ gs_p,
    const int* __restrict__ im_p,
    float* __restrict__ ws,
    float* __restrict__ out)
{
    const float gs = (float)(*gs_p);
    const float im = (float)(*im_p);
    const float im1 = im - 1.0f;

    float s_conf = 0.0f, s_coord = 0.0f, s_cls = 0.0f, s_iou = 0.0f, s_obj = 0.0f;

    const int base = blockIdx.x * 256 + threadIdx.x;

    #pragma unroll
    for (int it = 0; it < ITERS; ++it) {
        const int n = base + it * CELL_STRIDE;   // lane-adjacent cells
        const float4* pb = bb4 + (size_t)n * 3;
        const float4* pg = gt4 + (size_t)n * 3;

        const float4 b0 = pb[0];   // x1,y1,w1,h1
        const float4 b1 = pb[1];   // c1,x2,y2,w2
        const float4 b2 = pb[2];   // h2,c2,cls0,cls1
        const float4 g0 = pg[0];   // x,y,w,h
        const float4 g1 = pg[1];   // conf,l,u,r
        const float4 g2 = pg[2];   // d,obj,cls0,cls1

        const float c1 = b1.x;
        const float c2 = b2.y;
        const bool sel2 = c1 < c2;

        const float p0 = sel2 ? b1.y : b0.x;
        const float p1 = sel2 ? b1.z : b0.y;
        const float p2 = sel2 ? b1.w : b0.z;
        const float p3 = sel2 ? b2.x : b0.w;
        const float p4 = sel2 ? c2   : c1;    // sel_conf
        const float other = sel2 ? c1 : c2;   // other_conf

        const bool obj = (g2.y != 0.0f);
        const float objf = obj ? 1.0f : 0.0f;

        // confidence losses
        float conf_c = L_NOOBJ_C * other * other;
        const float dconf = g1.x - p4;
        conf_c += obj ? (dconf * dconf) : (L_NOOBJ_C * p4 * p4);
        s_conf += conf_c;

        // coord loss
        const float dx = g0.x - p0;
        const float dy = g0.y - p1;
        const float dw = sq_sqrt(g0.z) - sq_sqrt(p2);
        const float dh = sq_sqrt(g0.w) - sq_sqrt(p3);
        s_coord += objf * (L_COORD_C * (dx*dx + dy*dy + dw*dw + dh*dh));

        // class loss
        const float dc0 = g2.z - b2.z;
        const float dc1 = g2.w - b2.w;
        s_cls += objf * (dc0*dc0 + dc1*dc1);

        // IoU
        const int rem = n % CELLS_PER_IMG;
        const int gi = rem / S_DIM;
        const int gj = rem % S_DIM;
        const float px = truncf((float)gj * gs + p0 * gs);
        const float py = truncf((float)gi * gs + p1 * gs);
        const float pw = truncf(p2 * im);
        const float ph = truncf(p3 * im);
        const float pl = fmaxf(0.0f, px - pw * 0.5f);
        const float pu = fmaxf(0.0f, py - ph * 0.5f);
        const float pr = fminf(im1, px + pw * 0.5f);
        const float pd = fminf(im1, py + ph * 0.5f);
        const float pA = (pr - pl) * (pd - pu);
        const float gl = g1.y, gu = g1.z, gr = g1.w, gd = g2.x;
        const float gA = (gr - gl) * (gd - gu);
        const float lx = fmaxf(pl, gl);
        const float rx = fminf(pr, gr);
        const float uy = fmaxf(pu, gu);
        const float dy2 = fminf(pd, gd);
        const float inter = (rx - lx) * (dy2 - uy);
        const float iou = ((rx < lx) || (dy2 < uy)) ? 0.0f : inter / (pA + gA - inter);
        s_iou += objf * iou;

        s_obj += objf;
    }

    // wave reduction
    #pragma unroll
    for (int off = 32; off > 0; off >>= 1) {
        s_conf  += __shfl_down(s_conf,  off);
        s_coord += __shfl_down(s_coord, off);
        s_cls   += __shfl_down(s_cls,   off);
        s_iou   += __shfl_down(s_iou,   off);
        s_obj   += __shfl_down(s_obj,   off);
    }

    __shared__ float red[4][5];
    __shared__ int islast;
    const int w = threadIdx.x >> 6;
    const int l = threadIdx.x & 63;
    if (l == 0) {
        red[w][0] = s_conf;
        red[w][1] = s_coord;
        red[w][2] = s_cls;
        red[w][3] = s_iou;
        red[w][4] = s_obj;
    }
    __syncthreads();
    if (threadIdx.x == 0) {
        float t0 = 0, t1 = 0, t2 = 0, t3 = 0, t4 = 0;
        #pragma unroll
        for (int v = 0; v < 4; ++v) {
            t0 += red[v][0]; t1 += red[v][1]; t2 += red[v][2];
            t3 += red[v][3]; t4 += red[v][4];
        }
        const int r = blockIdx.x & (NROWS - 1);
        float* row = ws + (size_t)r * ROWF;     // private 64-B line per row
        atomicAdd(&row[0], t0);  // conf
        atomicAdd(&row[1], t1);  // coord
        atomicAdd(&row[2], t2);  // cls
        atomicAdd(&row[3], t3);  // iou
        atomicAdd(&row[4], t4);  // obj count

        // release-ordered row ticket (own 64-B line per row, <=36 adds each)
        int* ticket = (int*)((char*)ws + TICKET_BYTE + (size_t)r * 64);
        const int t = __hip_atomic_fetch_add(ticket, 1, __ATOMIC_RELEASE,
                                             __HIP_MEMORY_SCOPE_AGENT);
        int last = 0;
        if (t == BLOCKS_PER_ROW - 1) {
            // this row complete; bump rows-done (only 64 such adds total)
            unsigned* done = (unsigned*)((char*)ws + DONE_BYTE);
            const unsigned dv = __hip_atomic_fetch_add(done, 1u, __ATOMIC_ACQ_REL,
                                                       __HIP_MEMORY_SCOPE_AGENT);
            last = (dv == NROWS - 1);
        }
        islast = last;
    }
    __syncthreads();

    // the block that completed the final row reduces all 64 rows.
    // Reads use the atomic path (same coherence point as the adds).
    if (islast && threadIdx.x < 64) {
        float* row = ws + (size_t)threadIdx.x * ROWF;
        float a0 = atomicAdd(&row[0], 0.0f);
        float a1 = atomicAdd(&row[1], 0.0f);
        float a2 = atomicAdd(&row[2], 0.0f);
        float a3 = atomicAdd(&row[3], 0.0f);
        float a4 = atomicAdd(&row[4], 0.0f);
        #pragma unroll
        for (int off = 32; off > 0; off >>= 1) {
            a0 += __shfl_down(a0, off);
            a1 += __shfl_down(a1, off);
            a2 += __shfl_down(a2, off);
            a3 += __shfl_down(a3, off);
            a4 += __shfl_down(a4, off);
        }
        if (threadIdx.x == 0) {
            out[0] = a0 + a1 + a2;  // loss = conf + coord + cls
            out[1] = a1;            // l_coord
            out[2] = a0;            // loss_confidence
            out[3] = a2;            // l_cls
            out[4] = a3;            // iou_sum
            out[5] = a4;            // object_num
        }
    }
}

extern "C" void kernel_launch(void* const* d_in, const int* in_sizes, int n_in,
                              void* d_out, int out_size, void* d_ws, size_t ws_size,
                              hipStream_t stream) {
    const float4* bb4 = (const float4*)d_in[0];
    const float4* gt4 = (const float4*)d_in[1];
    const int* gs_p = (const int*)d_in[2];
    const int* im_p = (const int*)d_in[3];
    float* ws = (float*)d_ws;
    float* out = (float*)d_out;

    // zero rows + tickets + done counter (deterministic each launch)
    hipMemsetAsync(d_ws, 0, WS_BYTES, stream);

    yolo_loss_main<<<GRID_BLKS, 256, 0, stream>>>(bb4, gt4, gs_p, im_p, ws, out);
}

// Round 13
// 45.982 us; speedup vs baseline: 2.4404x; 2.2577x over previous
//
#include <hip/hip_runtime.h>

// YOLOv1 loss on MI355X — FINAL (revert to R8, the session best: 45.5 us).
// Direct strided float4 loads + spread-atomic accumulation + tiny finalize.
//
// Session findings (why this shape):
//  * Same-line atomic serialization (~17 ns each, queue-drain at kernel end)
//    dominated R1-R5 at 126-198 us. Spreading block partials across 64
//    distinct 64-B lines fixed it: 127 -> 46 us (R6).
//  * Front-end is NOT the limiter: block-LDS-staged lockstep (46.0), direct
//    9/CU (45.5), direct 8/CU+guard (46.3) all converge. Direct float4 loads
//    kept (simplest; FETCH=input-exact 111 MB, zero conflicts, no spills).
//  * Wave-private free-running staging REGRESSED (R7: FETCH +56%) — the
//    block-lockstep read window is what keeps L1/L2 effective.
//  * Fusing the finalize via last-block ticket REGRESSED twice (R10 +66 us
//    single-line ticket + threadfence; R12 +58 us spread ticket + release
//    atomics: per-block agent-scope ordering costs far more than the saved
//    dispatch). Separate 64-thread finalize kernel is the right call.
//  * Effective 4.97 TB/s = 79% of the measured float4-copy ceiling (6.29).
//
// Inputs: d_in[0] bb (16384,12,12,12) f32; d_in[1] gt (16384,12,12,1,12) f32;
//         d_in[2] grid_size int; d_in[3] img_size int.
// Output: 6 f32: loss, l_coord, loss_confidence, l_cls, iou_sum, object_num

#define S_DIM 12
#define CELLS_PER_IMG (S_DIM * S_DIM)      // 144
#define NCELLS (16384 * CELLS_PER_IMG)     // 2,359,296 = 2304 * 256 * 4
#define GRID_BLKS 2304                      // 9 blocks/CU
#define ITERS 4                             // 2304 * 256 * 4 = NCELLS exact
#define CELL_STRIDE (GRID_BLKS * 256)       // 589,824 cells between iterations
#define NROWS 64                            // spread-atomic rows (64 B apart)
#define ROWF 16                             // floats per row (64 B)
#define L_COORD_C 5.0f
#define L_NOOBJ_C 0.5f

__device__ __forceinline__ float sq_sqrt(float t) {
    return sqrtf(fmaxf(t, 0.0f) + 1e-08f);
}

__global__ __launch_bounds__(256) void yolo_loss_main(
    const float4* __restrict__ bb4,
    const float4* __restrict__ gt4,
    const int* __restrict__ gs_p,
    const int* __restrict__ im_p,
    float* __restrict__ ws)
{
    const float gs = (float)(*gs_p);
    const float im = (float)(*im_p);
    const float im1 = im - 1.0f;

    float s_conf = 0.0f, s_coord = 0.0f, s_cls = 0.0f, s_iou = 0.0f, s_obj = 0.0f;

    const int base = blockIdx.x * 256 + threadIdx.x;

    #pragma unroll
    for (int it = 0; it < ITERS; ++it) {
        const int n = base + it * CELL_STRIDE;   // lane-adjacent cells each iter
        const float4* pb = bb4 + (size_t)n * 3;  // 48 B per cell per input
        const float4* pg = gt4 + (size_t)n * 3;

        const float4 b0 = pb[0];   // x1,y1,w1,h1
        const float4 b1 = pb[1];   // c1,x2,y2,w2
        const float4 b2 = pb[2];   // h2,c2,cls0,cls1
        const float4 g0 = pg[0];   // x,y,w,h
        const float4 g1 = pg[1];   // conf,l,u,r
        const float4 g2 = pg[2];   // d,obj,cls0,cls1

        const float c1 = b1.x;
        const float c2 = b2.y;
        const bool sel2 = c1 < c2;

        const float p0 = sel2 ? b1.y : b0.x;
        const float p1 = sel2 ? b1.z : b0.y;
        const float p2 = sel2 ? b1.w : b0.z;
        const float p3 = sel2 ? b2.x : b0.w;
        const float p4 = sel2 ? c2   : c1;    // sel_conf
        const float other = sel2 ? c1 : c2;   // other_conf

        const bool obj = (g2.y != 0.0f);
        const float objf = obj ? 1.0f : 0.0f;

        // confidence losses
        float conf_c = L_NOOBJ_C * other * other;
        const float dconf = g1.x - p4;
        conf_c += obj ? (dconf * dconf) : (L_NOOBJ_C * p4 * p4);
        s_conf += conf_c;

        // coord loss
        const float dx = g0.x - p0;
        const float dy = g0.y - p1;
        const float dw = sq_sqrt(g0.z) - sq_sqrt(p2);
        const float dh = sq_sqrt(g0.w) - sq_sqrt(p3);
        s_coord += objf * (L_COORD_C * (dx*dx + dy*dy + dw*dw + dh*dh));

        // class loss
        const float dc0 = g2.z - b2.z;
        const float dc1 = g2.w - b2.w;
        s_cls += objf * (dc0*dc0 + dc1*dc1);

        // IoU
        const int rem = n % CELLS_PER_IMG;
        const int gi = rem / S_DIM;
        const int gj = rem % S_DIM;
        const float px = truncf((float)gj * gs + p0 * gs);
        const float py = truncf((float)gi * gs + p1 * gs);
        const float pw = truncf(p2 * im);
        const float ph = truncf(p3 * im);
        const float pl = fmaxf(0.0f, px - pw * 0.5f);
        const float pu = fmaxf(0.0f, py - ph * 0.5f);
        const float pr = fminf(im1, px + pw * 0.5f);
        const float pd = fminf(im1, py + ph * 0.5f);
        const float pA = (pr - pl) * (pd - pu);
        const float gl = g1.y, gu = g1.z, gr = g1.w, gd = g2.x;
        const float gA = (gr - gl) * (gd - gu);
        const float lx = fmaxf(pl, gl);
        const float rx = fminf(pr, gr);
        const float uy = fmaxf(pu, gu);
        const float dy2 = fminf(pd, gd);
        const float inter = (rx - lx) * (dy2 - uy);
        const float iou = ((rx < lx) || (dy2 < uy)) ? 0.0f : inter / (pA + gA - inter);
        s_iou += objf * iou;

        s_obj += objf;
    }

    // wave reduction
    #pragma unroll
    for (int off = 32; off > 0; off >>= 1) {
        s_conf  += __shfl_down(s_conf,  off);
        s_coord += __shfl_down(s_coord, off);
        s_cls   += __shfl_down(s_cls,   off);
        s_iou   += __shfl_down(s_iou,   off);
        s_obj   += __shfl_down(s_obj,   off);
    }

    __shared__ float red[4][5];
    const int w = threadIdx.x >> 6;
    const int l = threadIdx.x & 63;
    if (l == 0) {
        red[w][0] = s_conf;
        red[w][1] = s_coord;
        red[w][2] = s_cls;
        red[w][3] = s_iou;
        red[w][4] = s_obj;
    }
    __syncthreads();
    if (threadIdx.x == 0) {
        float t0 = 0, t1 = 0, t2 = 0, t3 = 0, t4 = 0;
        #pragma unroll
        for (int v = 0; v < 4; ++v) {
            t0 += red[v][0]; t1 += red[v][1]; t2 += red[v][2];
            t3 += red[v][3]; t4 += red[v][4];
        }
        // spread accumulation: row (blockIdx & 63), each row its own 64-B line
        float* row = ws + (size_t)(blockIdx.x & (NROWS - 1)) * ROWF;
        atomicAdd(&row[0], t0);  // conf (no_other + no_sel + conf_obj)
        atomicAdd(&row[1], t1);  // coord
        atomicAdd(&row[2], t2);  // cls
        atomicAdd(&row[3], t3);  // iou
        atomicAdd(&row[4], t4);  // obj count
    }
}

__global__ __launch_bounds__(64) void yolo_loss_finalize(
    const float* __restrict__ ws, float* __restrict__ out)
{
    const int l = threadIdx.x;   // 64 lanes, one row each
    const float* row = ws + (size_t)l * ROWF;
    float a0 = row[0], a1 = row[1], a2 = row[2], a3 = row[3], a4 = row[4];
    #pragma unroll
    for (int off = 32; off > 0; off >>= 1) {
        a0 += __shfl_down(a0, off);
        a1 += __shfl_down(a1, off);
        a2 += __shfl_down(a2, off);
        a3 += __shfl_down(a3, off);
        a4 += __shfl_down(a4, off);
    }
    if (l == 0) {
        out[0] = a0 + a1 + a2;  // loss = conf + coord + cls
        out[1] = a1;            // l_coord
        out[2] = a0;            // loss_confidence
        out[3] = a2;            // l_cls
        out[4] = a3;            // iou_sum
        out[5] = a4;            // object_num
    }
}

extern "C" void kernel_launch(void* const* d_in, const int* in_sizes, int n_in,
                              void* d_out, int out_size, void* d_ws, size_t ws_size,
                              hipStream_t stream) {
    const float4* bb4 = (const float4*)d_in[0];
    const float4* gt4 = (const float4*)d_in[1];
    const int* gs_p = (const int*)d_in[2];
    const int* im_p = (const int*)d_in[3];
    float* ws = (float*)d_ws;
    float* out = (float*)d_out;

    // zero the 4 KB accumulator region every launch (deterministic)
    hipMemsetAsync(d_ws, 0, NROWS * ROWF * sizeof(float), stream);

    yolo_loss_main<<<GRID_BLKS, 256, 0, stream>>>(bb4, gt4, gs_p, im_p, ws);
    yolo_loss_finalize<<<1, 64, 0, stream>>>(ws, out);
}